// Round 10
// baseline (2603.532 us; speedup 1.0000x reference)
//
#include <hip/hip_runtime.h>
#include <stdint.h>

typedef short s16x8 __attribute__((ext_vector_type(8)));
typedef float f32x4 __attribute__((ext_vector_type(4)));
typedef unsigned short u16;

#define MFMA16(a,b,c) __builtin_amdgcn_mfma_f32_16x16x32_bf16((a),(b),(c),0,0,0)
#define ACAP 1184   // key-cache capacity rows (>= 1152, mult of 32)

__device__ __forceinline__ u16 f2bf(float f) {
  union { float f; unsigned u; } v; v.f = f;
  return (u16)((v.u + 0x7FFFu + ((v.u >> 16) & 1u)) >> 16);
}
__device__ __forceinline__ float bf2f(u16 u) {
  union { float f; unsigned v; } x; x.v = ((unsigned)u) << 16; return x.f;
}

__device__ __forceinline__ float block_sum256(float v, float* lred) {
  #pragma unroll
  for (int d = 32; d >= 1; d >>= 1) v += __shfl_xor(v, d);
  __syncthreads();
  if ((threadIdx.x & 63) == 0) lred[threadIdx.x >> 6] = v;
  __syncthreads();
  return (lred[0] + lred[1]) + (lred[2] + lred[3]);
}

__device__ __forceinline__ float gelu_t(float x) {
  float u = 0.7978845608028654f * (x + 0.044715f * x * x * x);
  return 0.5f * x * (1.0f + tanhf(u));
}

// ---------------- split-precision GEMM: fp32-class via 3-term split-bf16 MFMA ----------------
// A = Ah + Al (bf16 pair), W split on the fly: D = Ah*Wh + Ah*Wl + Al*Wh (drop Al*Wl, ~2^-16 rel).
__global__ __launch_bounds__(256) void gemm3_k(
    const u16* __restrict__ Ah, const u16* __restrict__ Al, int lda,
    const float* __restrict__ W0, const float* __restrict__ W1, const float* __restrict__ W2,
    int e0, int e1, int ld0, int ld1, int ld2,
    float* __restrict__ out, int N, int kchunk, int Ktot)
{
  __shared__ float red[4 * 2048];
  const int n0 = blockIdx.x * 16;
  const int split = blockIdx.y;
  const float* W; int ldw, c0;
  if (n0 < e0)      { W = W0; ldw = ld0; c0 = n0; }
  else if (n0 < e1) { W = W1; ldw = ld1; c0 = n0 - e0; }
  else              { W = W2; ldw = ld2; c0 = n0 - e1; }
  const int w = threadIdx.x >> 6, l = threadIdx.x & 63;
  const int lr = l & 15, lh = l >> 4;
  const int wk = kchunk >> 2;
  const int k0 = split * kchunk + w * wk, k1 = k0 + wk;
  const u16* Abh = Ah + (size_t)lr * lda + 8 * lh;
  const u16* Abl = Al + (size_t)lr * lda + 8 * lh;
  const float* Wb = W + (size_t)(8 * lh) * ldw + (c0 + lr);

  f32x4 acc[8];
  #pragma unroll
  for (int i = 0; i < 8; i++) acc[i] = (f32x4){0.f,0.f,0.f,0.f};

  for (int k = k0; k < k1; k += 32) {
    s16x8 ah[8], al[8];
    #pragma unroll
    for (int mt = 0; mt < 8; mt++) {
      ah[mt] = *(const s16x8*)(Abh + (size_t)(16*mt)*lda + k);
      al[mt] = *(const s16x8*)(Abl + (size_t)(16*mt)*lda + k);
    }
    s16x8 bh, bl;
    #pragma unroll
    for (int jj = 0; jj < 8; jj++) {
      float wv = Wb[(size_t)(k + jj) * ldw];
      u16 hb = f2bf(wv);
      bh[jj] = (short)hb;
      bl[jj] = (short)f2bf(wv - bf2f(hb));
    }
    #pragma unroll
    for (int mt = 0; mt < 8; mt++) acc[mt] = MFMA16(ah[mt], bh, acc[mt]);
    #pragma unroll
    for (int mt = 0; mt < 8; mt++) acc[mt] = MFMA16(ah[mt], bl, acc[mt]);
    #pragma unroll
    for (int mt = 0; mt < 8; mt++) acc[mt] = MFMA16(al[mt], bh, acc[mt]);
  }
  #pragma unroll
  for (int mt = 0; mt < 8; mt++)
    #pragma unroll
    for (int r = 0; r < 4; r++)
      red[w * 2048 + (16*mt + 4*lh + r) * 16 + lr] = acc[mt][r];
  __syncthreads();
  const size_t ob = (size_t)split * (128 * (size_t)N) + n0;
  #pragma unroll
  for (int i = 0; i < 8; i++) {
    int e = threadIdx.x + 256 * i;
    int row = e >> 4, c = e & 15;
    float s = (red[e] + red[2048 + e]) + (red[4096 + e] + red[6144 + e]);
    out[ob + (size_t)row * N + c] = s;
  }
}

// ---------------- init: hs copy, hi/lo bf16(hs), hi/lo bf16 of rms(hs, w_in_ln[0]) ----------------
__global__ __launch_bounds__(256) void init_k(
    const float* __restrict__ hid, const float* __restrict__ w0,
    float* __restrict__ hs, u16* __restrict__ h0b, u16* __restrict__ h0l,
    u16* __restrict__ hbf, u16* __restrict__ hbl)
{
  __shared__ float lred[4];
  int s = blockIdx.x, t = threadIdx.x;
  float x[8]; float ss = 0.f;
  #pragma unroll
  for (int i = 0; i < 8; i++) {
    int j = t + 256 * i;
    float v = hid[(size_t)s * 2048 + j];
    x[i] = v; ss += v * v;
    hs[(size_t)s * 2048 + j] = v;
    u16 hi = f2bf(v);
    h0b[(size_t)s * 2048 + j] = hi;
    h0l[(size_t)s * 2048 + j] = f2bf(v - bf2f(hi));
  }
  ss = block_sum256(ss, lred);
  float rs = rsqrtf(ss * (1.f/2048.f) + 1e-6f);
  #pragma unroll
  for (int i = 0; i < 8; i++) {
    int j = t + 256 * i;
    float xn = x[i] * rs * w0[j];
    u16 hi = f2bf(xn);
    hbf[(size_t)s * 2048 + j] = hi;
    hbl[(size_t)s * 2048 + j] = f2bf(xn - bf2f(hi));
  }
}

// ---------------- PLE precompute ----------------
__global__ __launch_bounds__(256) void ple_norm_k(
    const float* __restrict__ proj, const float* __restrict__ raw,
    const float* __restrict__ wp, float* __restrict__ ple)
{
  __shared__ float lred[4];
  int b = blockIdx.x;
  int s = b / 35, lt = b % 35, t = threadIdx.x;
  size_t idx = (size_t)s * 8960 + lt * 256 + t;
  float p = proj[idx] * 0.022097086912079612f;
  float ss = block_sum256(p * p, lred);
  float rs = rsqrtf(ss * (1.f/256.f) + 1e-6f);
  ple[idx] = (p * rs * wp[t] + raw[idx]) * 0.7071067811865476f;
}

// ---------------- stage old KV: K rows -> hi/lo bf16, V -> transposed hi/lo bf16 VT[d][j] ----------------
__global__ __launch_bounds__(256) void fill_kv2_k(
    const float* __restrict__ oK, const float* __restrict__ oV,
    u16* __restrict__ Kh, u16* __restrict__ Kl,
    u16* __restrict__ VTh, u16* __restrict__ VTl,
    int olen, int ooff, int old_ld, int nA)
{
  __shared__ float tile[64][65];
  int b = blockIdx.x, t = threadIdx.x;
  if (b < nA) {
    // K rows: element-wise hi/lo split, coalesced
    size_t base = (size_t)b * 4096;
    #pragma unroll
    for (int i = 0; i < 16; i++) {
      size_t e = base + t + 256 * i;
      int kv = (int)(e / ((size_t)olen * 256));
      size_t rem = e - (size_t)kv * olen * 256;
      int j = (int)(rem >> 8), d = (int)(rem & 255);
      float v = oK[((size_t)kv * old_ld + ooff + j) * 256 + d];
      u16 hi = f2bf(v);
      size_t dst = (size_t)kv * (ACAP*256) + (size_t)j * 256 + d;
      Kh[dst] = hi;
      Kl[dst] = f2bf(v - bf2f(hi));
    }
  } else {
    // V transpose via 64x64 LDS tile, hi/lo split on store
    int tb = b - nA;
    int tj = olen >> 6;              // j-tiles per kv
    int per_kv = tj * 4;             // 4 d-tiles (256/64)
    int kv = tb / per_kv, rem = tb % per_kv;
    int j0 = (rem % tj) * 64, d0 = (rem / tj) * 64;
    #pragma unroll
    for (int i = 0; i < 16; i++) {
      int e = t + 256 * i;
      int jj = e >> 6, dd = e & 63;
      tile[jj][dd] = oV[((size_t)kv * old_ld + ooff + j0 + jj) * 256 + d0 + dd];
    }
    __syncthreads();
    #pragma unroll
    for (int i = 0; i < 16; i++) {
      int e = t + 256 * i;
      int dd = e >> 6, jj = e & 63;
      float v = tile[jj][dd];
      u16 hi = f2bf(v);
      size_t dst = (size_t)kv * (256*ACAP) + (size_t)(d0 + dd) * ACAP + (j0 + jj);
      VTh[dst] = hi;
      VTl[dst] = f2bf(v - bf2f(hi));
    }
  }
}

// ---------------- q/k rms+rope, v vnorm; hi/lo q + hi/lo caches + fp32 k/v outputs ----------------
__global__ __launch_bounds__(256) void prep_attn_k(
    const float* __restrict__ qkvP, int nsplit,
    const float* __restrict__ wq, const float* __restrict__ wk,
    const float* __restrict__ cosb, const float* __restrict__ sinb,
    u16* __restrict__ qh, u16* __restrict__ ql,
    float* __restrict__ outk, float* __restrict__ outv,
    u16* __restrict__ Kh, u16* __restrict__ Kl,
    u16* __restrict__ VTh, u16* __restrict__ VTl, int jbase)
{
  __shared__ float lred[4];
  __shared__ float xs[256];
  int s = blockIdx.x, t = threadIdx.x;
  const float* base = qkvP + (size_t)s * 3072;
  float c = cosb[s * 256 + t], sn = sinb[s * 256 + t];
  #pragma unroll 1
  for (int h = 0; h < 8; h++) {
    float v = 0.f;
    for (int sp = 0; sp < nsplit; sp++) v += base[(size_t)sp * (128*3072) + h * 256 + t];
    float ss = block_sum256(v * v, lred);
    float rs = rsqrtf(ss * (1.f/256.f) + 1e-6f);
    float xn = v * rs * wq[t];
    xs[t] = xn;
    __syncthreads();
    float pr = xs[t ^ 128];
    float ro = (t < 128) ? -pr : pr;
    float qv = xn * c + ro * sn;
    u16 hi = f2bf(qv);
    qh[((size_t)h * 128 + s) * 256 + t] = hi;
    ql[((size_t)h * 128 + s) * 256 + t] = f2bf(qv - bf2f(hi));
    __syncthreads();
  }
  #pragma unroll 1
  for (int g = 0; g < 2; g++) {
    float v = 0.f;
    for (int sp = 0; sp < nsplit; sp++) v += base[(size_t)sp * (128*3072) + 2048 + g * 256 + t];
    float ss = block_sum256(v * v, lred);
    float rs = rsqrtf(ss * (1.f/256.f) + 1e-6f);
    float xn = v * rs * wk[t];
    xs[t] = xn;
    __syncthreads();
    float pr = xs[t ^ 128];
    float ro = (t < 128) ? -pr : pr;
    float kq = xn * c + ro * sn;
    outk[(size_t)g * (128*256) + s * 256 + t] = kq;
    u16 khi = f2bf(kq);
    size_t kdst = (size_t)g * (ACAP*256) + (size_t)(jbase + s) * 256 + t;
    Kh[kdst] = khi;
    Kl[kdst] = f2bf(kq - bf2f(khi));
    __syncthreads();
    float vv = 0.f;
    for (int sp = 0; sp < nsplit; sp++) vv += base[(size_t)sp * (128*3072) + 2560 + g * 256 + t];
    float ss2 = block_sum256(vv * vv, lred);
    float rs2 = rsqrtf(ss2 * (1.f/256.f) + 1e-6f);
    float vn = vv * rs2;
    outv[(size_t)g * (128*256) + s * 256 + t] = vn;
    u16 vhi = f2bf(vn);
    size_t vdst = (size_t)g * (256*ACAP) + (size_t)t * ACAP + (jbase + s);
    VTh[vdst] = vhi;
    VTl[vdst] = f2bf(vn - bf2f(vhi));
  }
}

// ---------------- MFMA flash attention, fp32-class throughout ----------------
// QK^T: 3-term split-bf16 q,K. Softmax fp32. PV: 3-term split-bf16 P,V.
// launch_bounds(256,1): grid is 64 blocks (<=1 block/CU, 1 wave/SIMD), so occupancy is
// unaffected; lifting the VGPR cap toward 512 removes inner-loop scratch spill.
__global__ __launch_bounds__(256, 1) void attn5_k(
    const u16* __restrict__ qh, const u16* __restrict__ ql,
    const u16* __restrict__ Kh, const u16* __restrict__ Kl,
    const u16* __restrict__ VTh, const u16* __restrict__ VTl,
    u16* __restrict__ outbf, u16* __restrict__ outlo, int off)
{
  __shared__ float OW[3][16][256];
  __shared__ float MW[4][16];
  __shared__ float LW[4][16];
  __shared__ u16 Ph[4][16*32];
  __shared__ u16 Pl[4][16*32];
  int bx = blockIdx.x;
  int h = bx >> 3, qt = bx & 7;
  int kv = h >> 2;
  int s0 = qt * 16;
  int nkeys = off + s0 + 16;        // one past last potentially-valid key for this tile
  int w = threadIdx.x >> 6, l = threadIdx.x & 63;
  int lr = l & 15, lh = l >> 4;
  int ck = ((nkeys + 127) >> 7) << 5;   // per-wave key chunk, multiple of 32
  int jb = w * ck;
  int je = min(jb + ck, nkeys);
  const u16* Khb = Kh + (size_t)kv * (ACAP * 256);
  const u16* Klb = Kl + (size_t)kv * (ACAP * 256);
  const u16* Vhb = VTh + (size_t)kv * (256 * (size_t)ACAP);
  const u16* Vlb = VTl + (size_t)kv * (256 * (size_t)ACAP);

  // A-fragments of q: row = s0+lr, k-elem = 32*kk + 8*lh + jj
  s16x8 aqh[8], aql[8];
  {
    const u16* qrh = qh + ((size_t)h * 128 + s0 + lr) * 256 + 8 * lh;
    const u16* qrl = ql + ((size_t)h * 128 + s0 + lr) * 256 + 8 * lh;
    #pragma unroll
    for (int kk = 0; kk < 8; kk++) {
      aqh[kk] = *(const s16x8*)(qrh + kk * 32);
      aql[kk] = *(const s16x8*)(qrl + kk * 32);
    }
  }
  f32x4 accO[16];
  #pragma unroll
  for (int i = 0; i < 16; i++) accO[i] = (f32x4){0.f,0.f,0.f,0.f};
  float m_run[4], l_run[4];
  #pragma unroll
  for (int r = 0; r < 4; r++) { m_run[r] = -3.0e38f; l_run[r] = 0.f; }
  u16* Pwh = &Ph[w][0];
  u16* Pwl = &Pl[w][0];

  for (int j0 = jb; j0 < je; j0 += 32) {
    f32x4 lg[2];
    lg[0] = (f32x4){0.f,0.f,0.f,0.f};
    lg[1] = (f32x4){0.f,0.f,0.f,0.f};
    #pragma unroll
    for (int kk = 0; kk < 8; kk++) {
      const u16* kb0 = Khb + (size_t)(j0 + lr) * 256 + kk * 32 + 8 * lh;
      const u16* kb1 = Khb + (size_t)(j0 + 16 + lr) * 256 + kk * 32 + 8 * lh;
      const u16* kl0 = Klb + (size_t)(j0 + lr) * 256 + kk * 32 + 8 * lh;
      const u16* kl1 = Klb + (size_t)(j0 + 16 + lr) * 256 + kk * 32 + 8 * lh;
      s16x8 b0h = *(const s16x8*)kb0, b1h = *(const s16x8*)kb1;
      s16x8 b0l = *(const s16x8*)kl0, b1l = *(const s16x8*)kl1;
      lg[0] = MFMA16(aqh[kk], b0h, lg[0]);
      lg[1] = MFMA16(aqh[kk], b1h, lg[1]);
      lg[0] = MFMA16(aqh[kk], b0l, lg[0]);
      lg[1] = MFMA16(aqh[kk], b1l, lg[1]);
      lg[0] = MFMA16(aql[kk], b0h, lg[0]);
      lg[1] = MFMA16(aql[kk], b1h, lg[1]);
    }
    // masked online softmax (rows: s0 + 4*lh + r; valid iff j <= off + row)
    float tmax[4];
    #pragma unroll
    for (int r = 0; r < 4; r++) tmax[r] = -1.0e30f;
    #pragma unroll
    for (int tt = 0; tt < 2; tt++) {
      int j = j0 + 16 * tt + lr;
      #pragma unroll
      for (int r = 0; r < 4; r++)
        if (j <= off + s0 + 4 * lh + r) tmax[r] = fmaxf(tmax[r], lg[tt][r]);
    }
    #pragma unroll
    for (int d = 1; d < 16; d <<= 1)
      #pragma unroll
      for (int r = 0; r < 4; r++) tmax[r] = fmaxf(tmax[r], __shfl_xor(tmax[r], d));
    float scl[4], rsum[4];
    #pragma unroll
    for (int r = 0; r < 4; r++) {
      float mn = fmaxf(m_run[r], tmax[r]);
      scl[r] = __expf(m_run[r] - mn);     // 0 if m_run was -inf sentinel
      m_run[r] = mn;
      rsum[r] = 0.f;
    }
    #pragma unroll
    for (int tt = 0; tt < 2; tt++) {
      int j = j0 + 16 * tt + lr;
      #pragma unroll
      for (int r = 0; r < 4; r++) {
        bool valid = (j <= off + s0 + 4 * lh + r);
        float p = valid ? __expf(lg[tt][r] - m_run[r]) : 0.f;
        lg[tt][r] = p;
        rsum[r] += p;
      }
    }
    #pragma unroll
    for (int d = 1; d < 16; d <<= 1)
      #pragma unroll
      for (int r = 0; r < 4; r++) rsum[r] += __shfl_xor(rsum[r], d);
    #pragma unroll
    for (int r = 0; r < 4; r++) l_run[r] = l_run[r] * scl[r] + rsum[r];
    // P hi/lo (D-layout) -> LDS in A-layout order [qrow][key]
    #pragma unroll
    for (int tt = 0; tt < 2; tt++) {
      #pragma unroll
      for (int r = 0; r < 4; r++) {
        float p = lg[tt][r];
        u16 phi = f2bf(p);
        Pwh[(4 * lh + r) * 32 + 16 * tt + lr] = phi;
        Pwl[(4 * lh + r) * 32 + 16 * tt + lr] = f2bf(p - bf2f(phi));
      }
    }
    #pragma unroll
    for (int t2 = 0; t2 < 16; t2++)
      #pragma unroll
      for (int r = 0; r < 4; r++) accO[t2][r] *= scl[r];
    // PV: A = P hi/lo [16q x 32k] from LDS, B = V^T hi/lo fragment (contiguous per lane)
    s16x8 pah = *(const s16x8*)(Pwh + lr * 32 + 8 * lh);
    s16x8 pal = *(const s16x8*)(Pwl + lr * 32 + 8 * lh);
    #pragma unroll
    for (int t2 = 0; t2 < 16; t2++) {
      s16x8 bvh = *(const s16x8*)(Vhb + (size_t)(16 * t2 + lr) * ACAP + j0 + 8 * lh);
      s16x8 bvl = *(const s16x8*)(Vlb + (size_t)(16 * t2 + lr) * ACAP + j0 + 8 * lh);
      accO[t2] = MFMA16(pah, bvh, accO[t2]);
      accO[t2] = MFMA16(pah, bvl, accO[t2]);
      accO[t2] = MFMA16(pal, bvh, accO[t2]);
    }
  }
  if (w > 0) {
    #pragma unroll
    for (int t2 = 0; t2 < 16; t2++)
      #pragma unroll
      for (int r = 0; r < 4; r++)
        OW[w - 1][4 * lh + r][16 * t2 + lr] = accO[t2][r];
  }
  if (lr == 0) {
    #pragma unroll
    for (int r = 0; r < 4; r++) { MW[w][4 * lh + r] = m_run[r]; LW[w][4 * lh + r] = l_run[r]; }
  }
  __syncthreads();
  if (w == 0) {
    float ew[4][4], inv[4];
    #pragma unroll
    for (int r = 0; r < 4; r++) {
      int row = 4 * lh + r;
      float M = fmaxf(fmaxf(m_run[r], MW[1][row]), fmaxf(MW[2][row], MW[3][row]));
      ew[r][0] = __expf(m_run[r] - M);
      ew[r][1] = __expf(MW[1][row] - M);
      ew[r][2] = __expf(MW[2][row] - M);
      ew[r][3] = __expf(MW[3][row] - M);
      float L = l_run[r] * ew[r][0] + LW[1][row] * ew[r][1] + LW[2][row] * ew[r][2] + LW[3][row] * ew[r][3];
      inv[r] = 1.f / L;
    }
    #pragma unroll
    for (int t2 = 0; t2 < 16; t2++) {
      #pragma unroll
      for (int r = 0; r < 4; r++) {
        int row = 4 * lh + r, c = 16 * t2 + lr;
        float o = accO[t2][r] * ew[r][0] + OW[0][row][c] * ew[r][1]
                + OW[1][row][c] * ew[r][2] + OW[2][row][c] * ew[r][3];
        float val = o * inv[r];
        u16 hi = f2bf(val);
        outbf[(size_t)(s0 + row) * 2048 + h * 256 + c] = hi;
        outlo[(size_t)(s0 + row) * 2048 + h * 256 + c] = f2bf(val - bf2f(hi));
      }
    }
  }
}

// ---------------- residual + rms norm (+ optional second norm hi/lo or raw hi/lo, fp32 out) ----------------
__global__ __launch_bounds__(256) void norm_res_k(
    const float* __restrict__ parts, int nsplit,
    const float* __restrict__ wn, float* __restrict__ hs,
    const float* __restrict__ w2, u16* __restrict__ outbf, u16* __restrict__ outlo,
    const float* __restrict__ scp, float* __restrict__ outf)
{
  __shared__ float lred[4];
  int row = blockIdx.x, t = threadIdx.x;
  const float* pr = parts + (size_t)row * 2048;
  float x[8]; float ss = 0.f;
  #pragma unroll
  for (int i = 0; i < 8; i++) {
    int j = t + 256 * i;
    float v = 0.f;
    for (int sp = 0; sp < nsplit; sp++) v += pr[(size_t)sp * (128*2048) + j];
    x[i] = v; ss += v * v;
  }
  ss = block_sum256(ss, lred);
  float rs = rsqrtf(ss * (1.f/2048.f) + 1e-6f);
  float sc = scp ? scp[0] : 1.f;
  float y[8]; float ss2 = 0.f;
  #pragma unroll
  for (int i = 0; i < 8; i++) {
    int j = t + 256 * i;
    float v = (hs[(size_t)row * 2048 + j] + x[i] * rs * wn[j]) * sc;
    y[i] = v; ss2 += v * v;
    hs[(size_t)row * 2048 + j] = v;
    if (outf) outf[(size_t)row * 2048 + j] = v;
  }
  if (outbf) {
    if (w2) {
      ss2 = block_sum256(ss2, lred);
      float rs2 = rsqrtf(ss2 * (1.f/2048.f) + 1e-6f);
      #pragma unroll
      for (int i = 0; i < 8; i++) {
        int j = t + 256 * i;
        float xn = y[i] * rs2 * w2[j];
        u16 hi = f2bf(xn);
        outbf[(size_t)row * 2048 + j] = hi;
        if (outlo) outlo[(size_t)row * 2048 + j] = f2bf(xn - bf2f(hi));
      }
    } else {
      #pragma unroll
      for (int i = 0; i < 8; i++) {
        int j = t + 256 * i;
        u16 hi = f2bf(y[i]);
        outbf[(size_t)row * 2048 + j] = hi;
        if (outlo) outlo[(size_t)row * 2048 + j] = f2bf(y[i] - bf2f(hi));
      }
    }
  }
}

// ---------------- gelu(gate)*up -> hi/lo bf16 ----------------
__global__ __launch_bounds__(256) void mlp_act_k(
    const float* __restrict__ gu, int nsplit, u16* __restrict__ out, u16* __restrict__ outlo)
{
  int base = blockIdx.x * 1024 + threadIdx.x * 4;
  int row = base >> 12, j = base & 4095;
  float g[4] = {0,0,0,0}, u[4] = {0,0,0,0};
  for (int sp = 0; sp < nsplit; sp++) {
    const float4 gg = *(const float4*)(gu + (size_t)sp * (128*8192) + (size_t)row * 8192 + j);
    const float4 uu = *(const float4*)(gu + (size_t)sp * (128*8192) + (size_t)row * 8192 + 4096 + j);
    g[0]+=gg.x; g[1]+=gg.y; g[2]+=gg.z; g[3]+=gg.w;
    u[0]+=uu.x; u[1]+=uu.y; u[2]+=uu.z; u[3]+=uu.w;
  }
  size_t ob = (size_t)row * 4096 + j;
  #pragma unroll
  for (int q = 0; q < 4; q++) {
    float val = gelu_t(g[q]) * u[q];
    u16 hi = f2bf(val);
    out[ob + q] = hi;
    outlo[ob + q] = f2bf(val - bf2f(hi));
  }
}

// ---------------- gelu(pg)*ple_slice -> hi/lo bf16 ----------------
__global__ __launch_bounds__(256) void ple_act_k(
    const float* __restrict__ pgP, int nsplit, const float* __restrict__ ple,
    int layer, u16* __restrict__ gbf, u16* __restrict__ gbl)
{
  int s = blockIdx.x, t = threadIdx.x;
  float x = 0.f;
  for (int sp = 0; sp < nsplit; sp++) x += pgP[(size_t)sp * (128*256) + s * 256 + t];
  float val = gelu_t(x) * ple[(size_t)s * 8960 + layer * 256 + t];
  u16 hi = f2bf(val);
  gbf[s * 256 + t] = hi;
  gbl[s * 256 + t] = f2bf(val - bf2f(hi));
}

extern "C" void kernel_launch(void* const* d_in, const int* in_sizes, int n_in,
                              void* d_out, int out_size, void* d_ws, size_t ws_size,
                              hipStream_t stream)
{
  const float* hid   = (const float*)d_in[0];
  const float* raw   = (const float*)d_in[1];
  const float* cos_s = (const float*)d_in[2];
  const float* sin_s = (const float*)d_in[3];
  const float* cos_f = (const float*)d_in[4];
  const float* sin_f = (const float*)d_in[5];
  const float* Ksl   = (const float*)d_in[9];
  const float* Vsl   = (const float*)d_in[10];
  const float* Kfu   = (const float*)d_in[11];
  const float* Vfu   = (const float*)d_in[12];
  const float* Wq    = (const float*)d_in[13];
  const float* Wk    = (const float*)d_in[14];
  const float* Wv    = (const float*)d_in[15];
  const float* Wo    = (const float*)d_in[16];
  const float* w_in  = (const float*)d_in[17];
  const float* w_qn  = (const float*)d_in[18];
  const float* w_kn  = (const float*)d_in[19];
  const float* w_pa  = (const float*)d_in[20];
  const float* w_pf  = (const float*)d_in[21];
  const float* Wg    = (const float*)d_in[22];
  const float* Wu    = (const float*)d_in[23];
  const float* Wd    = (const float*)d_in[24];
  const float* w_ff  = (const float*)d_in[25];
  const float* Wpg   = (const float*)d_in[26];
  const float* Wpp   = (const float*)d_in[27];
  const float* w_pp  = (const float*)d_in[28];
  const float* lsc   = (const float*)d_in[29];
  const float* Wpm   = (const float*)d_in[30];
  const float* w_pn  = (const float*)d_in[31];

  char* ws = (char*)d_ws;
  size_t off = 0;
  auto alloc = [&](size_t b) { size_t o = off; off += (b + 255) & ~(size_t)255; return o; };
  size_t o_hs   = alloc(128*2048*4);
  size_t o_qkvP = alloc(2ull*128*3072*4);
  size_t o_t1P  = alloc(2ull*128*2048*4);
  size_t o_guP  = alloc(1ull*128*8192*4);
  size_t o_t2P  = alloc(2ull*128*2048*4);
  size_t o_pgP  = alloc(4ull*128*256*4);
  size_t o_t3P  = alloc(1ull*128*2048*4);
  size_t o_ple  = alloc(128ull*8960*4);
  size_t o_h0b  = alloc(128*2048*2);
  size_t o_h0l  = alloc(128*2048*2);
  size_t o_hb   = alloc(128*2048*2);
  size_t o_hbl  = alloc(128*2048*2);
  size_t o_h2b  = alloc(128*2048*2);
  size_t o_h2l  = alloc(128*2048*2);
  size_t o_hrb  = alloc(128*2048*2);
  size_t o_hrl  = alloc(128*2048*2);
  size_t o_ab   = alloc(128*2048*2);
  size_t o_abl  = alloc(128*2048*2);
  size_t o_mb   = alloc(128ull*4096*2);
  size_t o_mbl  = alloc(128ull*4096*2);
  size_t o_gb   = alloc(128*256*2);
  size_t o_gbl  = alloc(128*256*2);
  size_t o_qh   = alloc(8ull*128*256*2);
  size_t o_ql   = alloc(8ull*128*256*2);
  size_t o_Kh   = alloc(2ull*ACAP*256*2);
  size_t o_Kl   = alloc(2ull*ACAP*256*2);
  size_t o_VTh  = alloc(2ull*256*ACAP*2);
  size_t o_VTl  = alloc(2ull*256*ACAP*2);

  float* hs   = (float*)(ws + o_hs);
  float* qkvP = (float*)(ws + o_qkvP);
  float* t1P  = (float*)(ws + o_t1P);
  float* guP  = (float*)(ws + o_guP);
  float* t2P  = (float*)(ws + o_t2P);
  float* pgP  = (float*)(ws + o_pgP);
  float* t3P  = (float*)(ws + o_t3P);
  float* ple  = (float*)(ws + o_ple);
  float* proj = (float*)(ws + o_qkvP);   // overlay: proj (4.59MB) fits in qkvP+t1P (5.24MB), dead before layer 0
  u16* h0b = (u16*)(ws + o_h0b);
  u16* h0l = (u16*)(ws + o_h0l);
  u16* hb  = (u16*)(ws + o_hb);
  u16* hbl = (u16*)(ws + o_hbl);
  u16* h2b = (u16*)(ws + o_h2b);
  u16* h2l = (u16*)(ws + o_h2l);
  u16* hrb = (u16*)(ws + o_hrb);
  u16* hrl = (u16*)(ws + o_hrl);
  u16* ab  = (u16*)(ws + o_ab);
  u16* abl = (u16*)(ws + o_abl);
  u16* mb  = (u16*)(ws + o_mb);
  u16* mbl = (u16*)(ws + o_mbl);
  u16* gb  = (u16*)(ws + o_gb);
  u16* gbl = (u16*)(ws + o_gbl);
  u16* qhb = (u16*)(ws + o_qh);
  u16* qlb = (u16*)(ws + o_ql);
  u16* Khc = (u16*)(ws + o_Kh);
  u16* Klc = (u16*)(ws + o_Kl);
  u16* VThc = (u16*)(ws + o_VTh);
  u16* VTlc = (u16*)(ws + o_VTl);

  float* ouths = (float*)d_out;
  float* outk  = ouths + 128*2048;
  float* outv  = outk + 8*2*128*256;

  init_k<<<128, 256, 0, stream>>>(hid, w_in, hs, h0b, h0l, hb, hbl);
  gemm3_k<<<dim3(560,1), 256, 0, stream>>>(h0b, h0l, 2048, Wpm, Wpm, Wpm,
      8960, 8960, 8960, 8960, 8960, proj, 8960, 2048, 2048);
  ple_norm_k<<<128*35, 256, 0, stream>>>(proj, raw, w_pn, ple);

  for (int i = 0; i < 8; i++) {
    bool full = (i == 5);
    int si = (i < 5) ? i : i - 1;
    const float* cs = full ? cos_f : cos_s;
    const float* sn = full ? sin_f : sin_s;
    int jbase = full ? 1024 : 384;
    if (full) {
      // nA = 2*1024*256/4096 = 128; V-transpose blocks = 2*(1024/64)*4 = 128
      fill_kv2_k<<<256, 256, 0, stream>>>(Kfu, Vfu, Khc, Klc, VThc, VTlc, 1024, 0, 2048, 128);
    } else {
      // nA = 2*384*256/4096 = 48; V-transpose blocks = 2*(384/64)*4 = 48
      fill_kv2_k<<<96, 256, 0, stream>>>(Ksl + (size_t)si*2*512*256, Vsl + (size_t)si*2*512*256,
                                         Khc, Klc, VThc, VTlc, 384, 128, 512, 48);
    }
    gemm3_k<<<dim3(192,2), 256, 0, stream>>>(hb, hbl, 2048,
        Wq + (size_t)i*2048*2048, Wk + (size_t)i*2048*512, Wv + (size_t)i*2048*512,
        2048, 2560, 2048, 512, 512, qkvP, 3072, 1024, 2048);
    prep_attn_k<<<128, 256, 0, stream>>>(qkvP, 2, w_qn + i*256, w_kn + i*256, cs, sn,
        qhb, qlb, outk + (size_t)i*65536, outv + (size_t)i*65536, Khc, Klc, VThc, VTlc, jbase);
    attn5_k<<<64, 256, 0, stream>>>(qhb, qlb, Khc, Klc, VThc, VTlc, ab, abl, jbase);
    gemm3_k<<<dim3(128,2), 256, 0, stream>>>(ab, abl, 2048,
        Wo + (size_t)i*2048*2048, Wo, Wo, 2048, 2048, 2048, 2048, 2048,
        t1P, 2048, 1024, 2048);
    norm_res_k<<<128, 256, 0, stream>>>(t1P, 2, w_pa + i*2048, hs,
        w_pf + i*2048, h2b, h2l, nullptr, nullptr);
    gemm3_k<<<dim3(512,1), 256, 0, stream>>>(h2b, h2l, 2048,
        Wg + (size_t)i*2048*4096, Wu + (size_t)i*2048*4096, Wu,
        4096, 8192, 4096, 4096, 4096, guP, 8192, 2048, 2048);
    mlp_act_k<<<512, 256, 0, stream>>>(guP, 1, mb, mbl);
    gemm3_k<<<dim3(128,2), 256, 0, stream>>>(mb, mbl, 4096,
        Wd + (size_t)i*4096*2048, Wd, Wd, 2048, 2048, 2048, 2048, 2048,
        t2P, 2048, 2048, 4096);
    norm_res_k<<<128, 256, 0, stream>>>(t2P, 2, w_ff + i*2048, hs,
        nullptr, hrb, hrl, nullptr, nullptr);
    gemm3_k<<<dim3(16,4), 256, 0, stream>>>(hrb, hrl, 2048,
        Wpg + (size_t)i*2048*256, Wpg, Wpg, 256, 256, 256, 256, 256,
        pgP, 256, 512, 2048);
    ple_act_k<<<128, 256, 0, stream>>>(pgP, 4, ple, i, gb, gbl);
    gemm3_k<<<dim3(128,1), 256, 0, stream>>>(gb, gbl, 256,
        Wpp + (size_t)i*256*2048, Wpp, Wpp, 2048, 2048, 2048, 2048, 2048,
        t3P, 2048, 256, 256);
    norm_res_k<<<128, 256, 0, stream>>>(t3P, 1, w_pp + i*2048, hs,
        (i < 7) ? (w_in + (i+1)*2048) : nullptr,
        (i < 7) ? hb : nullptr,
        (i < 7) ? hbl : nullptr,
        lsc + i, (i == 7) ? ouths : nullptr);
  }
}

// Round 11
// 2324.355 us; speedup vs baseline: 1.1201x; 1.1201x over previous
//
#include <hip/hip_runtime.h>
#include <stdint.h>

typedef short s16x8 __attribute__((ext_vector_type(8)));
typedef float f32x4 __attribute__((ext_vector_type(4)));
typedef unsigned short u16;

#define MFMA16(a,b,c) __builtin_amdgcn_mfma_f32_16x16x32_bf16((a),(b),(c),0,0,0)
#define ACAP 1184   // key-cache capacity rows (>= 1152, mult of 32)

__device__ __forceinline__ u16 f2bf(float f) {
  union { float f; unsigned u; } v; v.f = f;
  return (u16)((v.u + 0x7FFFu + ((v.u >> 16) & 1u)) >> 16);
}
__device__ __forceinline__ float bf2f(u16 u) {
  union { float f; unsigned v; } x; x.v = ((unsigned)u) << 16; return x.f;
}

__device__ __forceinline__ float block_sum256(float v, float* lred) {
  #pragma unroll
  for (int d = 32; d >= 1; d >>= 1) v += __shfl_xor(v, d);
  __syncthreads();
  if ((threadIdx.x & 63) == 0) lred[threadIdx.x >> 6] = v;
  __syncthreads();
  return (lred[0] + lred[1]) + (lred[2] + lred[3]);
}

__device__ __forceinline__ float gelu_t(float x) {
  float u = 0.7978845608028654f * (x + 0.044715f * x * x * x);
  return 0.5f * x * (1.0f + tanhf(u));
}

// ---------------- split-precision GEMM: fp32-class via 3-term split-bf16 MFMA ----------------
// A = Ah + Al (bf16 pair), W split on the fly: D = Ah*Wh + Ah*Wl + Al*Wh (drop Al*Wl, ~2^-16 rel).
// W (the HBM stream) is software-prefetched one k-iteration ahead so its ~900cyc latency
// hides under the 24-MFMA + split-VALU cluster. A is L2-resident, loaded in-loop.
__global__ __launch_bounds__(256) void gemm3_k(
    const u16* __restrict__ Ah, const u16* __restrict__ Al, int lda,
    const float* __restrict__ W0, const float* __restrict__ W1, const float* __restrict__ W2,
    int e0, int e1, int ld0, int ld1, int ld2,
    float* __restrict__ out, int N, int kchunk, int Ktot)
{
  __shared__ float red[4 * 2048];
  const int n0 = blockIdx.x * 16;
  const int split = blockIdx.y;
  const float* W; int ldw, c0;
  if (n0 < e0)      { W = W0; ldw = ld0; c0 = n0; }
  else if (n0 < e1) { W = W1; ldw = ld1; c0 = n0 - e0; }
  else              { W = W2; ldw = ld2; c0 = n0 - e1; }
  const int w = threadIdx.x >> 6, l = threadIdx.x & 63;
  const int lr = l & 15, lh = l >> 4;
  const int wk = kchunk >> 2;
  const int k0 = split * kchunk + w * wk, k1 = k0 + wk;
  const u16* Abh = Ah + (size_t)lr * lda + 8 * lh;
  const u16* Abl = Al + (size_t)lr * lda + 8 * lh;
  const float* Wb = W + (size_t)(8 * lh) * ldw + (c0 + lr);

  f32x4 acc[8];
  #pragma unroll
  for (int i = 0; i < 8; i++) acc[i] = (f32x4){0.f,0.f,0.f,0.f};

  float bc[8];
  #pragma unroll
  for (int jj = 0; jj < 8; jj++) bc[jj] = Wb[(size_t)(k0 + jj) * ldw];

  for (int k = k0; k < k1; k += 32) {
    s16x8 ah[8], al[8];
    #pragma unroll
    for (int mt = 0; mt < 8; mt++) {
      ah[mt] = *(const s16x8*)(Abh + (size_t)(16*mt)*lda + k);
      al[mt] = *(const s16x8*)(Abl + (size_t)(16*mt)*lda + k);
    }
    float bn[8];
    if (k + 32 < k1) {
      #pragma unroll
      for (int jj = 0; jj < 8; jj++) bn[jj] = Wb[(size_t)(k + 32 + jj) * ldw];
    }
    s16x8 bh, bl;
    #pragma unroll
    for (int jj = 0; jj < 8; jj++) {
      u16 hb = f2bf(bc[jj]);
      bh[jj] = (short)hb;
      bl[jj] = (short)f2bf(bc[jj] - bf2f(hb));
    }
    #pragma unroll
    for (int mt = 0; mt < 8; mt++) acc[mt] = MFMA16(ah[mt], bh, acc[mt]);
    #pragma unroll
    for (int mt = 0; mt < 8; mt++) acc[mt] = MFMA16(ah[mt], bl, acc[mt]);
    #pragma unroll
    for (int mt = 0; mt < 8; mt++) acc[mt] = MFMA16(al[mt], bh, acc[mt]);
    if (k + 32 < k1) {
      #pragma unroll
      for (int jj = 0; jj < 8; jj++) bc[jj] = bn[jj];
    }
  }
  #pragma unroll
  for (int mt = 0; mt < 8; mt++)
    #pragma unroll
    for (int r = 0; r < 4; r++)
      red[w * 2048 + (16*mt + 4*lh + r) * 16 + lr] = acc[mt][r];
  __syncthreads();
  const size_t ob = (size_t)split * (128 * (size_t)N) + n0;
  #pragma unroll
  for (int i = 0; i < 8; i++) {
    int e = threadIdx.x + 256 * i;
    int row = e >> 4, c = e & 15;
    float s = (red[e] + red[2048 + e]) + (red[4096 + e] + red[6144 + e]);
    out[ob + (size_t)row * N + c] = s;
  }
}

// ---------------- init: hs copy, hi/lo bf16(hs), hi/lo bf16 of rms(hs, w_in_ln[0]) ----------------
__global__ __launch_bounds__(256) void init_k(
    const float* __restrict__ hid, const float* __restrict__ w0,
    float* __restrict__ hs, u16* __restrict__ h0b, u16* __restrict__ h0l,
    u16* __restrict__ hbf, u16* __restrict__ hbl)
{
  __shared__ float lred[4];
  int s = blockIdx.x, t = threadIdx.x;
  float x[8]; float ss = 0.f;
  #pragma unroll
  for (int i = 0; i < 8; i++) {
    int j = t + 256 * i;
    float v = hid[(size_t)s * 2048 + j];
    x[i] = v; ss += v * v;
    hs[(size_t)s * 2048 + j] = v;
    u16 hi = f2bf(v);
    h0b[(size_t)s * 2048 + j] = hi;
    h0l[(size_t)s * 2048 + j] = f2bf(v - bf2f(hi));
  }
  ss = block_sum256(ss, lred);
  float rs = rsqrtf(ss * (1.f/2048.f) + 1e-6f);
  #pragma unroll
  for (int i = 0; i < 8; i++) {
    int j = t + 256 * i;
    float xn = x[i] * rs * w0[j];
    u16 hi = f2bf(xn);
    hbf[(size_t)s * 2048 + j] = hi;
    hbl[(size_t)s * 2048 + j] = f2bf(xn - bf2f(hi));
  }
}

// ---------------- PLE precompute ----------------
__global__ __launch_bounds__(256) void ple_norm_k(
    const float* __restrict__ proj, const float* __restrict__ raw,
    const float* __restrict__ wp, float* __restrict__ ple)
{
  __shared__ float lred[4];
  int b = blockIdx.x;
  int s = b / 35, lt = b % 35, t = threadIdx.x;
  size_t idx = (size_t)s * 8960 + lt * 256 + t;
  float p = proj[idx] * 0.022097086912079612f;
  float ss = block_sum256(p * p, lred);
  float rs = rsqrtf(ss * (1.f/256.f) + 1e-6f);
  ple[idx] = (p * rs * wp[t] + raw[idx]) * 0.7071067811865476f;
}

// ---------------- stage old KV: K rows -> hi/lo bf16, V -> transposed hi/lo bf16 VT[d][j] ----------------
__global__ __launch_bounds__(256) void fill_kv2_k(
    const float* __restrict__ oK, const float* __restrict__ oV,
    u16* __restrict__ Kh, u16* __restrict__ Kl,
    u16* __restrict__ VTh, u16* __restrict__ VTl,
    int olen, int ooff, int old_ld, int nA)
{
  __shared__ float tile[64][65];
  int b = blockIdx.x, t = threadIdx.x;
  if (b < nA) {
    size_t base = (size_t)b * 4096;
    #pragma unroll
    for (int i = 0; i < 16; i++) {
      size_t e = base + t + 256 * i;
      int kv = (int)(e / ((size_t)olen * 256));
      size_t rem = e - (size_t)kv * olen * 256;
      int j = (int)(rem >> 8), d = (int)(rem & 255);
      float v = oK[((size_t)kv * old_ld + ooff + j) * 256 + d];
      u16 hi = f2bf(v);
      size_t dst = (size_t)kv * (ACAP*256) + (size_t)j * 256 + d;
      Kh[dst] = hi;
      Kl[dst] = f2bf(v - bf2f(hi));
    }
  } else {
    int tb = b - nA;
    int tj = olen >> 6;              // j-tiles per kv
    int per_kv = tj * 4;             // 4 d-tiles (256/64)
    int kv = tb / per_kv, rem = tb % per_kv;
    int j0 = (rem % tj) * 64, d0 = (rem / tj) * 64;
    #pragma unroll
    for (int i = 0; i < 16; i++) {
      int e = t + 256 * i;
      int jj = e >> 6, dd = e & 63;
      tile[jj][dd] = oV[((size_t)kv * old_ld + ooff + j0 + jj) * 256 + d0 + dd];
    }
    __syncthreads();
    #pragma unroll
    for (int i = 0; i < 16; i++) {
      int e = t + 256 * i;
      int dd = e >> 6, jj = e & 63;
      float v = tile[jj][dd];
      u16 hi = f2bf(v);
      size_t dst = (size_t)kv * (256*ACAP) + (size_t)(d0 + dd) * ACAP + (j0 + jj);
      VTh[dst] = hi;
      VTl[dst] = f2bf(v - bf2f(hi));
    }
  }
}

// ---------------- q/k rms+rope, v vnorm; hi/lo q + hi/lo caches + fp32 k/v outputs ----------------
__global__ __launch_bounds__(256) void prep_attn_k(
    const float* __restrict__ qkvP, int nsplit,
    const float* __restrict__ wq, const float* __restrict__ wk,
    const float* __restrict__ cosb, const float* __restrict__ sinb,
    u16* __restrict__ qh, u16* __restrict__ ql,
    float* __restrict__ outk, float* __restrict__ outv,
    u16* __restrict__ Kh, u16* __restrict__ Kl,
    u16* __restrict__ VTh, u16* __restrict__ VTl, int jbase)
{
  __shared__ float lred[4];
  __shared__ float xs[256];
  int s = blockIdx.x, t = threadIdx.x;
  const float* base = qkvP + (size_t)s * 3072;
  float c = cosb[s * 256 + t], sn = sinb[s * 256 + t];
  #pragma unroll 1
  for (int h = 0; h < 8; h++) {
    float v = 0.f;
    for (int sp = 0; sp < nsplit; sp++) v += base[(size_t)sp * (128*3072) + h * 256 + t];
    float ss = block_sum256(v * v, lred);
    float rs = rsqrtf(ss * (1.f/256.f) + 1e-6f);
    float xn = v * rs * wq[t];
    xs[t] = xn;
    __syncthreads();
    float pr = xs[t ^ 128];
    float ro = (t < 128) ? -pr : pr;
    float qv = xn * c + ro * sn;
    u16 hi = f2bf(qv);
    qh[((size_t)h * 128 + s) * 256 + t] = hi;
    ql[((size_t)h * 128 + s) * 256 + t] = f2bf(qv - bf2f(hi));
    __syncthreads();
  }
  #pragma unroll 1
  for (int g = 0; g < 2; g++) {
    float v = 0.f;
    for (int sp = 0; sp < nsplit; sp++) v += base[(size_t)sp * (128*3072) + 2048 + g * 256 + t];
    float ss = block_sum256(v * v, lred);
    float rs = rsqrtf(ss * (1.f/256.f) + 1e-6f);
    float xn = v * rs * wk[t];
    xs[t] = xn;
    __syncthreads();
    float pr = xs[t ^ 128];
    float ro = (t < 128) ? -pr : pr;
    float kq = xn * c + ro * sn;
    outk[(size_t)g * (128*256) + s * 256 + t] = kq;
    u16 khi = f2bf(kq);
    size_t kdst = (size_t)g * (ACAP*256) + (size_t)(jbase + s) * 256 + t;
    Kh[kdst] = khi;
    Kl[kdst] = f2bf(kq - bf2f(khi));
    __syncthreads();
    float vv = 0.f;
    for (int sp = 0; sp < nsplit; sp++) vv += base[(size_t)sp * (128*3072) + 2560 + g * 256 + t];
    float ss2 = block_sum256(vv * vv, lred);
    float rs2 = rsqrtf(ss2 * (1.f/256.f) + 1e-6f);
    float vn = vv * rs2;
    outv[(size_t)g * (128*256) + s * 256 + t] = vn;
    u16 vhi = f2bf(vn);
    size_t vdst = (size_t)g * (256*ACAP) + (size_t)t * ACAP + (jbase + s);
    VTh[vdst] = vhi;
    VTl[vdst] = f2bf(vn - bf2f(vhi));
  }
}

// ---------------- MFMA flash attention, 4-way key-split across blocks ----------------
// grid = 256 blocks: bx -> (h, qt, ks). Block handles keys [ks*4*cw, (ks+1)*4*cw) with its
// 4 waves; writes UNNORMALIZED partial O~ (scaled to block max M) + per-row M, L.
// A separate combine kernel merges the 4 key-splits. Empty splits write (0, -3e38, 0),
// which the exp-weights annihilate exactly.
__global__ __launch_bounds__(256) void attn6_k(
    const u16* __restrict__ qh, const u16* __restrict__ ql,
    const u16* __restrict__ Kh, const u16* __restrict__ Kl,
    const u16* __restrict__ VTh, const u16* __restrict__ VTl,
    float* __restrict__ Opart, float* __restrict__ ML, int off)
{
  __shared__ float OW[3][16][256];
  __shared__ float MW[4][16];
  __shared__ float LW[4][16];
  __shared__ u16 Ph[4][16*32];
  __shared__ u16 Pl[4][16*32];
  int bx = blockIdx.x;
  int ks = bx & 3;
  int b64 = bx >> 2;
  int h = b64 >> 3, qt = b64 & 7;
  int kv = h >> 2;
  int s0 = qt * 16;
  int nkeys = off + s0 + 16;        // one past last potentially-valid key for this tile
  int w = threadIdx.x >> 6, l = threadIdx.x & 63;
  int lr = l & 15, lh = l >> 4;
  int cw = ((nkeys + 511) >> 9) << 5;   // per-wave chunk over 16 chunks total, mult of 32
  int g = ks * 4 + w;
  int jb = g * cw;
  int je = min(jb + cw, nkeys);
  const u16* Khb = Kh + (size_t)kv * (ACAP * 256);
  const u16* Klb = Kl + (size_t)kv * (ACAP * 256);
  const u16* Vhb = VTh + (size_t)kv * (256 * (size_t)ACAP);
  const u16* Vlb = VTl + (size_t)kv * (256 * (size_t)ACAP);

  // A-fragments of q: row = s0+lr, k-elem = 32*kk + 8*lh + jj
  s16x8 aqh[8], aql[8];
  {
    const u16* qrh = qh + ((size_t)h * 128 + s0 + lr) * 256 + 8 * lh;
    const u16* qrl = ql + ((size_t)h * 128 + s0 + lr) * 256 + 8 * lh;
    #pragma unroll
    for (int kk = 0; kk < 8; kk++) {
      aqh[kk] = *(const s16x8*)(qrh + kk * 32);
      aql[kk] = *(const s16x8*)(qrl + kk * 32);
    }
  }
  f32x4 accO[16];
  #pragma unroll
  for (int i = 0; i < 16; i++) accO[i] = (f32x4){0.f,0.f,0.f,0.f};
  float m_run[4], l_run[4];
  #pragma unroll
  for (int r = 0; r < 4; r++) { m_run[r] = -3.0e38f; l_run[r] = 0.f; }
  u16* Pwh = &Ph[w][0];
  u16* Pwl = &Pl[w][0];

  for (int j0 = jb; j0 < je; j0 += 32) {
    f32x4 lg[2];
    lg[0] = (f32x4){0.f,0.f,0.f,0.f};
    lg[1] = (f32x4){0.f,0.f,0.f,0.f};
    #pragma unroll
    for (int kk = 0; kk < 8; kk++) {
      const u16* kb0 = Khb + (size_t)(j0 + lr) * 256 + kk * 32 + 8 * lh;
      const u16* kb1 = Khb + (size_t)(j0 + 16 + lr) * 256 + kk * 32 + 8 * lh;
      const u16* kl0 = Klb + (size_t)(j0 + lr) * 256 + kk * 32 + 8 * lh;
      const u16* kl1 = Klb + (size_t)(j0 + 16 + lr) * 256 + kk * 32 + 8 * lh;
      s16x8 b0h = *(const s16x8*)kb0, b1h = *(const s16x8*)kb1;
      s16x8 b0l = *(const s16x8*)kl0, b1l = *(const s16x8*)kl1;
      lg[0] = MFMA16(aqh[kk], b0h, lg[0]);
      lg[1] = MFMA16(aqh[kk], b1h, lg[1]);
      lg[0] = MFMA16(aqh[kk], b0l, lg[0]);
      lg[1] = MFMA16(aqh[kk], b1l, lg[1]);
      lg[0] = MFMA16(aql[kk], b0h, lg[0]);
      lg[1] = MFMA16(aql[kk], b1h, lg[1]);
    }
    // masked online softmax (rows: s0 + 4*lh + r; valid iff j <= off + row)
    float tmax[4];
    #pragma unroll
    for (int r = 0; r < 4; r++) tmax[r] = -1.0e30f;
    #pragma unroll
    for (int tt = 0; tt < 2; tt++) {
      int j = j0 + 16 * tt + lr;
      #pragma unroll
      for (int r = 0; r < 4; r++)
        if (j <= off + s0 + 4 * lh + r) tmax[r] = fmaxf(tmax[r], lg[tt][r]);
    }
    #pragma unroll
    for (int d = 1; d < 16; d <<= 1)
      #pragma unroll
      for (int r = 0; r < 4; r++) tmax[r] = fmaxf(tmax[r], __shfl_xor(tmax[r], d));
    float scl[4], rsum[4];
    #pragma unroll
    for (int r = 0; r < 4; r++) {
      float mn = fmaxf(m_run[r], tmax[r]);
      scl[r] = __expf(m_run[r] - mn);
      m_run[r] = mn;
      rsum[r] = 0.f;
    }
    #pragma unroll
    for (int tt = 0; tt < 2; tt++) {
      int j = j0 + 16 * tt + lr;
      #pragma unroll
      for (int r = 0; r < 4; r++) {
        bool valid = (j <= off + s0 + 4 * lh + r);
        float p = valid ? __expf(lg[tt][r] - m_run[r]) : 0.f;
        lg[tt][r] = p;
        rsum[r] += p;
      }
    }
    #pragma unroll
    for (int d = 1; d < 16; d <<= 1)
      #pragma unroll
      for (int r = 0; r < 4; r++) rsum[r] += __shfl_xor(rsum[r], d);
    #pragma unroll
    for (int r = 0; r < 4; r++) l_run[r] = l_run[r] * scl[r] + rsum[r];
    #pragma unroll
    for (int tt = 0; tt < 2; tt++) {
      #pragma unroll
      for (int r = 0; r < 4; r++) {
        float p = lg[tt][r];
        u16 phi = f2bf(p);
        Pwh[(4 * lh + r) * 32 + 16 * tt + lr] = phi;
        Pwl[(4 * lh + r) * 32 + 16 * tt + lr] = f2bf(p - bf2f(phi));
      }
    }
    #pragma unroll
    for (int t2 = 0; t2 < 16; t2++)
      #pragma unroll
      for (int r = 0; r < 4; r++) accO[t2][r] *= scl[r];
    s16x8 pah = *(const s16x8*)(Pwh + lr * 32 + 8 * lh);
    s16x8 pal = *(const s16x8*)(Pwl + lr * 32 + 8 * lh);
    #pragma unroll
    for (int t2 = 0; t2 < 16; t2++) {
      s16x8 bvh = *(const s16x8*)(Vhb + (size_t)(16 * t2 + lr) * ACAP + j0 + 8 * lh);
      s16x8 bvl = *(const s16x8*)(Vlb + (size_t)(16 * t2 + lr) * ACAP + j0 + 8 * lh);
      accO[t2] = MFMA16(pah, bvh, accO[t2]);
      accO[t2] = MFMA16(pah, bvl, accO[t2]);
      accO[t2] = MFMA16(pal, bvh, accO[t2]);
    }
  }
  if (w > 0) {
    #pragma unroll
    for (int t2 = 0; t2 < 16; t2++)
      #pragma unroll
      for (int r = 0; r < 4; r++)
        OW[w - 1][4 * lh + r][16 * t2 + lr] = accO[t2][r];
  }
  if (lr == 0) {
    #pragma unroll
    for (int r = 0; r < 4; r++) { MW[w][4 * lh + r] = m_run[r]; LW[w][4 * lh + r] = l_run[r]; }
  }
  __syncthreads();
  if (w == 0) {
    float ew[4][4];
    float Mrow[4], Lrow[4];
    #pragma unroll
    for (int r = 0; r < 4; r++) {
      int row = 4 * lh + r;
      float M = fmaxf(fmaxf(m_run[r], MW[1][row]), fmaxf(MW[2][row], MW[3][row]));
      ew[r][0] = __expf(m_run[r] - M);
      ew[r][1] = __expf(MW[1][row] - M);
      ew[r][2] = __expf(MW[2][row] - M);
      ew[r][3] = __expf(MW[3][row] - M);
      Lrow[r] = l_run[r] * ew[r][0] + LW[1][row] * ew[r][1] + LW[2][row] * ew[r][2] + LW[3][row] * ew[r][3];
      Mrow[r] = M;
    }
    float* Ob = Opart + (size_t)bx * 4096;
    #pragma unroll
    for (int t2 = 0; t2 < 16; t2++) {
      #pragma unroll
      for (int r = 0; r < 4; r++) {
        int row = 4 * lh + r, c = 16 * t2 + lr;
        float o = accO[t2][r] * ew[r][0] + OW[0][row][c] * ew[r][1]
                + OW[1][row][c] * ew[r][2] + OW[2][row][c] * ew[r][3];
        Ob[row * 256 + c] = o;
      }
    }
    if (lr == 0) {
      #pragma unroll
      for (int r = 0; r < 4; r++) {
        int row = 4 * lh + r;
        ML[bx * 32 + row] = Mrow[r];
        ML[bx * 32 + 16 + row] = Lrow[r];
      }
    }
  }
}

// ---------------- combine 4 key-split partials -> normalized attn out (hi/lo bf16) ----------------
__global__ __launch_bounds__(256) void attn_comb_k(
    const float* __restrict__ Opart, const float* __restrict__ ML,
    u16* __restrict__ outbf, u16* __restrict__ outlo)
{
  int b = blockIdx.x;            // h*8 + qt
  int h = b >> 3, qt = b & 7, s0 = qt * 16;
  int c = threadIdx.x;           // column 0..255
  #pragma unroll 1
  for (int row = 0; row < 16; row++) {
    float m[4], lv[4];
    #pragma unroll
    for (int ks = 0; ks < 4; ks++) {
      m[ks]  = ML[(b * 4 + ks) * 32 + row];
      lv[ks] = ML[(b * 4 + ks) * 32 + 16 + row];
    }
    float Mg = fmaxf(fmaxf(m[0], m[1]), fmaxf(m[2], m[3]));
    float L = 0.f, o = 0.f;
    #pragma unroll
    for (int ks = 0; ks < 4; ks++) {
      float e = __expf(m[ks] - Mg);
      L += lv[ks] * e;
      o += Opart[((size_t)(b * 4 + ks)) * 4096 + row * 256 + c] * e;
    }
    float val = o / L;
    u16 hi = f2bf(val);
    outbf[(size_t)(s0 + row) * 2048 + h * 256 + c] = hi;
    outlo[(size_t)(s0 + row) * 2048 + h * 256 + c] = f2bf(val - bf2f(hi));
  }
}

// ---------------- residual + rms norm (+ optional second norm hi/lo or raw hi/lo, fp32 out) ----------------
__global__ __launch_bounds__(256) void norm_res_k(
    const float* __restrict__ parts, int nsplit,
    const float* __restrict__ wn, float* __restrict__ hs,
    const float* __restrict__ w2, u16* __restrict__ outbf, u16* __restrict__ outlo,
    const float* __restrict__ scp, float* __restrict__ outf)
{
  __shared__ float lred[4];
  int row = blockIdx.x, t = threadIdx.x;
  const float* pr = parts + (size_t)row * 2048;
  float x[8]; float ss = 0.f;
  #pragma unroll
  for (int i = 0; i < 8; i++) {
    int j = t + 256 * i;
    float v = 0.f;
    for (int sp = 0; sp < nsplit; sp++) v += pr[(size_t)sp * (128*2048) + j];
    x[i] = v; ss += v * v;
  }
  ss = block_sum256(ss, lred);
  float rs = rsqrtf(ss * (1.f/2048.f) + 1e-6f);
  float sc = scp ? scp[0] : 1.f;
  float y[8]; float ss2 = 0.f;
  #pragma unroll
  for (int i = 0; i < 8; i++) {
    int j = t + 256 * i;
    float v = (hs[(size_t)row * 2048 + j] + x[i] * rs * wn[j]) * sc;
    y[i] = v; ss2 += v * v;
    hs[(size_t)row * 2048 + j] = v;
    if (outf) outf[(size_t)row * 2048 + j] = v;
  }
  if (outbf) {
    if (w2) {
      ss2 = block_sum256(ss2, lred);
      float rs2 = rsqrtf(ss2 * (1.f/2048.f) + 1e-6f);
      #pragma unroll
      for (int i = 0; i < 8; i++) {
        int j = t + 256 * i;
        float xn = y[i] * rs2 * w2[j];
        u16 hi = f2bf(xn);
        outbf[(size_t)row * 2048 + j] = hi;
        if (outlo) outlo[(size_t)row * 2048 + j] = f2bf(xn - bf2f(hi));
      }
    } else {
      #pragma unroll
      for (int i = 0; i < 8; i++) {
        int j = t + 256 * i;
        u16 hi = f2bf(y[i]);
        outbf[(size_t)row * 2048 + j] = hi;
        if (outlo) outlo[(size_t)row * 2048 + j] = f2bf(y[i] - bf2f(hi));
      }
    }
  }
}

// ---------------- gelu(gate)*up -> hi/lo bf16 ----------------
__global__ __launch_bounds__(256) void mlp_act_k(
    const float* __restrict__ gu, int nsplit, u16* __restrict__ out, u16* __restrict__ outlo)
{
  int base = blockIdx.x * 1024 + threadIdx.x * 4;
  int row = base >> 12, j = base & 4095;
  float g[4] = {0,0,0,0}, u[4] = {0,0,0,0};
  for (int sp = 0; sp < nsplit; sp++) {
    const float4 gg = *(const float4*)(gu + (size_t)sp * (128*8192) + (size_t)row * 8192 + j);
    const float4 uu = *(const float4*)(gu + (size_t)sp * (128*8192) + (size_t)row * 8192 + 4096 + j);
    g[0]+=gg.x; g[1]+=gg.y; g[2]+=gg.z; g[3]+=gg.w;
    u[0]+=uu.x; u[1]+=uu.y; u[2]+=uu.z; u[3]+=uu.w;
  }
  size_t ob = (size_t)row * 4096 + j;
  #pragma unroll
  for (int q = 0; q < 4; q++) {
    float val = gelu_t(g[q]) * u[q];
    u16 hi = f2bf(val);
    out[ob + q] = hi;
    outlo[ob + q] = f2bf(val - bf2f(hi));
  }
}

// ---------------- gelu(pg)*ple_slice -> hi/lo bf16 ----------------
__global__ __launch_bounds__(256) void ple_act_k(
    const float* __restrict__ pgP, int nsplit, const float* __restrict__ ple,
    int layer, u16* __restrict__ gbf, u16* __restrict__ gbl)
{
  int s = blockIdx.x, t = threadIdx.x;
  float x = 0.f;
  for (int sp = 0; sp < nsplit; sp++) x += pgP[(size_t)sp * (128*256) + s * 256 + t];
  float val = gelu_t(x) * ple[(size_t)s * 8960 + layer * 256 + t];
  u16 hi = f2bf(val);
  gbf[s * 256 + t] = hi;
  gbl[s * 256 + t] = f2bf(val - bf2f(hi));
}

extern "C" void kernel_launch(void* const* d_in, const int* in_sizes, int n_in,
                              void* d_out, int out_size, void* d_ws, size_t ws_size,
                              hipStream_t stream)
{
  const float* hid   = (const float*)d_in[0];
  const float* raw   = (const float*)d_in[1];
  const float* cos_s = (const float*)d_in[2];
  const float* sin_s = (const float*)d_in[3];
  const float* cos_f = (const float*)d_in[4];
  const float* sin_f = (const float*)d_in[5];
  const float* Ksl   = (const float*)d_in[9];
  const float* Vsl   = (const float*)d_in[10];
  const float* Kfu   = (const float*)d_in[11];
  const float* Vfu   = (const float*)d_in[12];
  const float* Wq    = (const float*)d_in[13];
  const float* Wk    = (const float*)d_in[14];
  const float* Wv    = (const float*)d_in[15];
  const float* Wo    = (const float*)d_in[16];
  const float* w_in  = (const float*)d_in[17];
  const float* w_qn  = (const float*)d_in[18];
  const float* w_kn  = (const float*)d_in[19];
  const float* w_pa  = (const float*)d_in[20];
  const float* w_pf  = (const float*)d_in[21];
  const float* Wg    = (const float*)d_in[22];
  const float* Wu    = (const float*)d_in[23];
  const float* Wd    = (const float*)d_in[24];
  const float* w_ff  = (const float*)d_in[25];
  const float* Wpg   = (const float*)d_in[26];
  const float* Wpp   = (const float*)d_in[27];
  const float* w_pp  = (const float*)d_in[28];
  const float* lsc   = (const float*)d_in[29];
  const float* Wpm   = (const float*)d_in[30];
  const float* w_pn  = (const float*)d_in[31];

  char* ws = (char*)d_ws;
  size_t off = 0;
  auto alloc = [&](size_t b) { size_t o = off; off += (b + 255) & ~(size_t)255; return o; };
  size_t o_hs   = alloc(128*2048*4);
  size_t o_qkvP = alloc(2ull*128*3072*4);
  size_t o_t1P  = alloc(2ull*128*2048*4);
  size_t o_guP  = alloc(1ull*128*8192*4);
  size_t o_t2P  = alloc(2ull*128*2048*4);
  size_t o_pgP  = alloc(4ull*128*256*4);
  size_t o_t3P  = alloc(1ull*128*2048*4);
  size_t o_ple  = alloc(128ull*8960*4);
  size_t o_h0b  = alloc(128*2048*2);
  size_t o_h0l  = alloc(128*2048*2);
  size_t o_hb   = alloc(128*2048*2);
  size_t o_hbl  = alloc(128*2048*2);
  size_t o_h2b  = alloc(128*2048*2);
  size_t o_h2l  = alloc(128*2048*2);
  size_t o_hrb  = alloc(128*2048*2);
  size_t o_hrl  = alloc(128*2048*2);
  size_t o_ab   = alloc(128*2048*2);
  size_t o_abl  = alloc(128*2048*2);
  size_t o_mb   = alloc(128ull*4096*2);
  size_t o_mbl  = alloc(128ull*4096*2);
  size_t o_gb   = alloc(128*256*2);
  size_t o_gbl  = alloc(128*256*2);
  size_t o_qh   = alloc(8ull*128*256*2);
  size_t o_ql   = alloc(8ull*128*256*2);
  size_t o_Kh   = alloc(2ull*ACAP*256*2);
  size_t o_Kl   = alloc(2ull*ACAP*256*2);
  size_t o_VTh  = alloc(2ull*256*ACAP*2);
  size_t o_VTl  = alloc(2ull*256*ACAP*2);
  size_t o_Op   = alloc(256ull*4096*4);
  size_t o_ML   = alloc(256ull*32*4);

  float* hs   = (float*)(ws + o_hs);
  float* qkvP = (float*)(ws + o_qkvP);
  float* t1P  = (float*)(ws + o_t1P);
  float* guP  = (float*)(ws + o_guP);
  float* t2P  = (float*)(ws + o_t2P);
  float* pgP  = (float*)(ws + o_pgP);
  float* t3P  = (float*)(ws + o_t3P);
  float* ple  = (float*)(ws + o_ple);
  float* proj = (float*)(ws + o_qkvP);   // overlay: proj (4.59MB) fits in qkvP+t1P (5.24MB), dead before layer 0
  u16* h0b = (u16*)(ws + o_h0b);
  u16* h0l = (u16*)(ws + o_h0l);
  u16* hb  = (u16*)(ws + o_hb);
  u16* hbl = (u16*)(ws + o_hbl);
  u16* h2b = (u16*)(ws + o_h2b);
  u16* h2l = (u16*)(ws + o_h2l);
  u16* hrb = (u16*)(ws + o_hrb);
  u16* hrl = (u16*)(ws + o_hrl);
  u16* ab  = (u16*)(ws + o_ab);
  u16* abl = (u16*)(ws + o_abl);
  u16* mb  = (u16*)(ws + o_mb);
  u16* mbl = (u16*)(ws + o_mbl);
  u16* gb  = (u16*)(ws + o_gb);
  u16* gbl = (u16*)(ws + o_gbl);
  u16* qhb = (u16*)(ws + o_qh);
  u16* qlb = (u16*)(ws + o_ql);
  u16* Khc = (u16*)(ws + o_Kh);
  u16* Klc = (u16*)(ws + o_Kl);
  u16* VThc = (u16*)(ws + o_VTh);
  u16* VTlc = (u16*)(ws + o_VTl);
  float* Opart = (float*)(ws + o_Op);
  float* MLb   = (float*)(ws + o_ML);

  float* ouths = (float*)d_out;
  float* outk  = ouths + 128*2048;
  float* outv  = outk + 8*2*128*256;

  init_k<<<128, 256, 0, stream>>>(hid, w_in, hs, h0b, h0l, hb, hbl);
  gemm3_k<<<dim3(560,1), 256, 0, stream>>>(h0b, h0l, 2048, Wpm, Wpm, Wpm,
      8960, 8960, 8960, 8960, 8960, proj, 8960, 2048, 2048);
  ple_norm_k<<<128*35, 256, 0, stream>>>(proj, raw, w_pn, ple);

  for (int i = 0; i < 8; i++) {
    bool full = (i == 5);
    int si = (i < 5) ? i : i - 1;
    const float* cs = full ? cos_f : cos_s;
    const float* sn = full ? sin_f : sin_s;
    int jbase = full ? 1024 : 384;
    if (full) {
      fill_kv2_k<<<256, 256, 0, stream>>>(Kfu, Vfu, Khc, Klc, VThc, VTlc, 1024, 0, 2048, 128);
    } else {
      fill_kv2_k<<<96, 256, 0, stream>>>(Ksl + (size_t)si*2*512*256, Vsl + (size_t)si*2*512*256,
                                         Khc, Klc, VThc, VTlc, 384, 128, 512, 48);
    }
    gemm3_k<<<dim3(192,2), 256, 0, stream>>>(hb, hbl, 2048,
        Wq + (size_t)i*2048*2048, Wk + (size_t)i*2048*512, Wv + (size_t)i*2048*512,
        2048, 2560, 2048, 512, 512, qkvP, 3072, 1024, 2048);
    prep_attn_k<<<128, 256, 0, stream>>>(qkvP, 2, w_qn + i*256, w_kn + i*256, cs, sn,
        qhb, qlb, outk + (size_t)i*65536, outv + (size_t)i*65536, Khc, Klc, VThc, VTlc, jbase);
    attn6_k<<<256, 256, 0, stream>>>(qhb, qlb, Khc, Klc, VThc, VTlc, Opart, MLb, jbase);
    attn_comb_k<<<64, 256, 0, stream>>>(Opart, MLb, ab, abl);
    gemm3_k<<<dim3(128,2), 256, 0, stream>>>(ab, abl, 2048,
        Wo + (size_t)i*2048*2048, Wo, Wo, 2048, 2048, 2048, 2048, 2048,
        t1P, 2048, 1024, 2048);
    norm_res_k<<<128, 256, 0, stream>>>(t1P, 2, w_pa + i*2048, hs,
        w_pf + i*2048, h2b, h2l, nullptr, nullptr);
    gemm3_k<<<dim3(512,1), 256, 0, stream>>>(h2b, h2l, 2048,
        Wg + (size_t)i*2048*4096, Wu + (size_t)i*2048*4096, Wu,
        4096, 8192, 4096, 4096, 4096, guP, 8192, 2048, 2048);
    mlp_act_k<<<512, 256, 0, stream>>>(guP, 1, mb, mbl);
    gemm3_k<<<dim3(128,2), 256, 0, stream>>>(mb, mbl, 4096,
        Wd + (size_t)i*4096*2048, Wd, Wd, 2048, 2048, 2048, 2048, 2048,
        t2P, 2048, 2048, 4096);
    norm_res_k<<<128, 256, 0, stream>>>(t2P, 2, w_ff + i*2048, hs,
        nullptr, hrb, hrl, nullptr, nullptr);
    gemm3_k<<<dim3(16,4), 256, 0, stream>>>(hrb, hrl, 2048,
        Wpg + (size_t)i*2048*256, Wpg, Wpg, 256, 256, 256, 256, 256,
        pgP, 256, 512, 2048);
    ple_act_k<<<128, 256, 0, stream>>>(pgP, 4, ple, i, gb, gbl);
    gemm3_k<<<dim3(128,1), 256, 0, stream>>>(gb, gbl, 256,
        Wpp + (size_t)i*256*2048, Wpp, Wpp, 2048, 2048, 2048, 2048, 2048,
        t3P, 2048, 256, 256);
    norm_res_k<<<128, 256, 0, stream>>>(t3P, 1, w_pp + i*2048, hs,
        (i < 7) ? (w_in + (i+1)*2048) : nullptr,
        (i < 7) ? hb : nullptr,
        (i < 7) ? hbl : nullptr,
        lsc + i, (i == 7) ? ouths : nullptr);
  }
}